// Round 1
// baseline (680.577 us; speedup 1.0000x reference)
//
#include <hip/hip_runtime.h>
#include <math.h>

#define D_IN  128
#define D_H   128
#define D_OUT 64
#define CAP   64   // fixed per-node in-edge capacity; Poisson(16) => P(deg>=64) ~ 1e-19

// ---------------- CSR build (fixed capacity, no prefix sum) ----------------
__global__ __launch_bounds__(256) void k_fill(const int* __restrict__ src,
                                              const int* __restrict__ dst,
                                              unsigned* __restrict__ cnt,
                                              int* __restrict__ csr, int E)
{
    int e = blockIdx.x * 256 + threadIdx.x;
    if (e >= E) return;
    int s = src[e], d = dst[e];
    unsigned pos = atomicAdd(&cnt[d], 1u);
    if (pos < CAP) csr[(size_t)d * CAP + pos] = s;
}

__global__ __launch_bounds__(256) void k_dinv(const unsigned* __restrict__ cnt,
                                              float* __restrict__ dinv, int N)
{
    int v = blockIdx.x * 256 + threadIdx.x;
    if (v >= N) return;
    dinv[v] = rsqrtf((float)(cnt[v] + 1u));   // +1 self-loop; always > 0
}

// ---------------- GEMM: out[r][c] = (sum_k X[r][k]*W[k][c]) * (SCALE?dinv[r]:1) ----
// K=128 fixed. Block: 256 threads, 32 rows. Thread: 4 rows (rl+8i) x CPT cols.
template<int M, bool SCALE>
__global__ __launch_bounds__(256) void k_gemm(const float* __restrict__ X,
                                              const float* __restrict__ W,
                                              const float* __restrict__ dinv,
                                              float* __restrict__ out, int N)
{
    constexpr int K = 128;
    constexpr int CPT = M / 32;          // 4 (M=128) or 2 (M=64)
    __shared__ float Ws[K * M];          // 64KB or 32KB

    const int tid = threadIdx.x;
    for (int idx = tid; idx < K * M / 4; idx += 256)
        reinterpret_cast<float4*>(Ws)[idx] = reinterpret_cast<const float4*>(W)[idx];
    __syncthreads();

    const int cg = tid & 31;             // 32 col groups
    const int rl = tid >> 5;             // 8 row lanes
    const int rbase = blockIdx.x * 32;

    int rr[4];
#pragma unroll
    for (int i = 0; i < 4; ++i) {
        int r = rbase + rl + 8 * i;
        rr[i] = (r < N) ? r : (N - 1);   // clamp (stores are guarded)
    }

    float acc[4][CPT];
#pragma unroll
    for (int i = 0; i < 4; ++i)
#pragma unroll
        for (int c = 0; c < CPT; ++c) acc[i][c] = 0.f;

    const float4* Xg = reinterpret_cast<const float4*>(X);

    for (int kq = 0; kq < K / 4; ++kq) {
        float4 xq[4];
#pragma unroll
        for (int i = 0; i < 4; ++i)
            xq[i] = Xg[(size_t)rr[i] * (K / 4) + kq];
#pragma unroll
        for (int kk = 0; kk < 4; ++kk) {
            float wv[CPT];
            const float* wrow = &Ws[(kq * 4 + kk) * M + cg * CPT];
            if constexpr (CPT == 4) {
                float4 w4 = *reinterpret_cast<const float4*>(wrow);
                wv[0] = w4.x; wv[1] = w4.y; wv[2] = w4.z; wv[3] = w4.w;
            } else {
                float2 w2 = *reinterpret_cast<const float2*>(wrow);
                wv[0] = w2.x; wv[1] = w2.y;
            }
#pragma unroll
            for (int i = 0; i < 4; ++i) {
                const float* xf = reinterpret_cast<const float*>(&xq[i]);
                float xv = xf[kk];
#pragma unroll
                for (int c = 0; c < CPT; ++c) acc[i][c] += xv * wv[c];
            }
        }
    }

#pragma unroll
    for (int i = 0; i < 4; ++i) {
        int r = rbase + rl + 8 * i;
        if (r >= N) continue;
        float s = SCALE ? dinv[r] : 1.f;
        float* orow = &out[(size_t)r * M + cg * CPT];
        if constexpr (CPT == 4) {
            float4 o; o.x = acc[i][0] * s; o.y = acc[i][1] * s;
            o.z = acc[i][2] * s; o.w = acc[i][3] * s;
            *reinterpret_cast<float4*>(orow) = o;
        } else {
            float2 o; o.x = acc[i][0] * s; o.y = acc[i][1] * s;
            *reinterpret_cast<float2*>(orow) = o;
        }
    }
}

// ---------------- Layer-1 aggregation + bias + SELU + pre-scale ----------------
// one wave per node, float2 per lane (128 feats). H rows are pre-scaled by dinv[src].
__global__ __launch_bounds__(256) void k_agg1(const float* __restrict__ H,
                                              const int* __restrict__ csr,
                                              const unsigned* __restrict__ cnt,
                                              const float* __restrict__ dinv,
                                              const float* __restrict__ b1,
                                              float* __restrict__ out, int N)
{
    const int wave = threadIdx.x >> 6;
    const int lane = threadIdx.x & 63;
    const int n = blockIdx.x * 4 + wave;
    if (n >= N) return;

    const float2* H2v = reinterpret_cast<const float2*>(H);
    float2 acc = H2v[(size_t)n * 64 + lane];            // self loop term
    unsigned c = cnt[n]; if (c > CAP) c = CAP;
    const int* lst = csr + (size_t)n * CAP;
    for (unsigned i = 0; i < c; ++i) {
        int s = lst[i];
        float2 v = H2v[(size_t)s * 64 + lane];
        acc.x += v.x; acc.y += v.y;
    }
    const float d = dinv[n];
    const float2 b = reinterpret_cast<const float2*>(b1)[lane];
    float ax = acc.x * d + b.x;
    float ay = acc.y * d + b.y;
    const float SC = 1.0507009873554805f, AL = 1.6732632423543773f;
    ax = (ax > 0.f) ? SC * ax : SC * AL * (expf(ax) - 1.f);
    ay = (ay > 0.f) ? SC * ay : SC * AL * (expf(ay) - 1.f);
    float2 o; o.x = ax * d; o.y = ay * d;               // fold dinv for layer 2
    reinterpret_cast<float2*>(out)[(size_t)n * 64 + lane] = o;
}

// ---------------- Layer-2 aggregation + bias + log_softmax ----------------
// one wave per node, 1 float per lane (64 feats).
__global__ __launch_bounds__(256) void k_agg2(const float* __restrict__ H,
                                              const int* __restrict__ csr,
                                              const unsigned* __restrict__ cnt,
                                              const float* __restrict__ dinv,
                                              const float* __restrict__ b2,
                                              float* __restrict__ out, int N)
{
    const int wave = threadIdx.x >> 6;
    const int lane = threadIdx.x & 63;
    const int n = blockIdx.x * 4 + wave;
    if (n >= N) return;

    float acc = H[(size_t)n * 64 + lane];               // self loop term
    unsigned c = cnt[n]; if (c > CAP) c = CAP;
    const int* lst = csr + (size_t)n * CAP;
    for (unsigned i = 0; i < c; ++i) {
        int s = lst[i];
        acc += H[(size_t)s * 64 + lane];
    }
    float t = acc * dinv[n] + b2[lane];

    float m = t;
#pragma unroll
    for (int off = 32; off > 0; off >>= 1) m = fmaxf(m, __shfl_xor(m, off));
    float e = expf(t - m);
    float ssum = e;
#pragma unroll
    for (int off = 32; off > 0; off >>= 1) ssum += __shfl_xor(ssum, off);
    out[(size_t)n * 64 + lane] = t - m - logf(ssum);
}

// ---------------- host ----------------
extern "C" void kernel_launch(void* const* d_in, const int* in_sizes, int n_in,
                              void* d_out, int out_size, void* d_ws, size_t ws_size,
                              hipStream_t stream)
{
    const float* x  = (const float*)d_in[0];
    const int*   ei = (const int*)  d_in[1];
    const float* W1 = (const float*)d_in[2];
    const float* b1 = (const float*)d_in[3];
    const float* W2 = (const float*)d_in[4];
    const float* b2 = (const float*)d_in[5];
    float* out = (float*)d_out;

    const int N = in_sizes[0] / D_IN;
    const int E = in_sizes[1] / 2;
    const int* src = ei;
    const int* dst = ei + E;

    char* ws = (char*)d_ws;
    size_t off = 0;
    auto take = [&](size_t bytes) -> void* {
        void* p = ws + off;
        off = (off + bytes + 255) & ~(size_t)255;
        return p;
    };
    unsigned* cnt  = (unsigned*)take((size_t)N * 4);
    float*    dinv = (float*)   take((size_t)N * 4);
    int*      csr  = (int*)     take((size_t)N * CAP * 4);
    float*    bufA = (float*)   take((size_t)N * D_H * 4);   // H1 pre-scaled
    float*    bufB = (float*)   take((size_t)N * D_H * 4);   // selu out, pre-scaled
    float*    bufC = bufA;                                   // reuse for H2

    hipMemsetAsync(cnt, 0, (size_t)N * 4, stream);
    k_fill<<<(E + 255) / 256, 256, 0, stream>>>(src, dst, cnt, csr, E);
    k_dinv<<<(N + 255) / 256, 256, 0, stream>>>(cnt, dinv, N);
    k_gemm<D_H, true ><<<(N + 31) / 32, 256, 0, stream>>>(x,    W1, dinv, bufA, N);
    k_agg1<<<(N + 3) / 4, 256, 0, stream>>>(bufA, csr, cnt, dinv, b1, bufB, N);
    k_gemm<D_OUT, false><<<(N + 31) / 32, 256, 0, stream>>>(bufB, W2, dinv, bufC, N);
    k_agg2<<<(N + 3) / 4, 256, 0, stream>>>(bufC, csr, cnt, dinv, b2, out, N);
}

// Round 2
// 544.586 us; speedup vs baseline: 1.2497x; 1.2497x over previous
//
#include <hip/hip_runtime.h>
#include <math.h>

#define D_IN  128
#define D_H   128
#define D_OUT 64
#define CAP   64   // fixed per-node in-edge capacity; Poisson(16) => P(deg>=64) ~ 1e-19

// ---------- bf16 helpers (storage bf16, math f32) ----------
__device__ inline float bf_lo(unsigned p) { return __builtin_bit_cast(float, p << 16); }
__device__ inline float bf_hi(unsigned p) { return __builtin_bit_cast(float, p & 0xffff0000u); }
__device__ inline unsigned f2bf_bits(float f) {            // RNE, returns bits in low 16
    unsigned u = __builtin_bit_cast(unsigned, f);
    return (u + 0x7fffu + ((u >> 16) & 1u)) >> 16;
}
__device__ inline unsigned pack_bf2(float x, float y) {
    return f2bf_bits(x) | (f2bf_bits(y) << 16);
}

// ---------------- CSR build (fixed capacity, no prefix sum) ----------------
__global__ __launch_bounds__(256) void k_fill(const int* __restrict__ src,
                                              const int* __restrict__ dst,
                                              unsigned* __restrict__ cnt,
                                              int* __restrict__ csr, int E)
{
    int e = blockIdx.x * 256 + threadIdx.x;
    if (e >= E) return;
    int s = src[e], d = dst[e];
    unsigned pos = atomicAdd(&cnt[d], 1u);
    if (pos < CAP) csr[(size_t)d * CAP + pos] = s;
}

__global__ __launch_bounds__(256) void k_dinv(const unsigned* __restrict__ cnt,
                                              float* __restrict__ dinv, int N)
{
    int v = blockIdx.x * 256 + threadIdx.x;
    if (v >= N) return;
    dinv[v] = rsqrtf((float)(cnt[v] + 1u));   // +1 self-loop; always > 0
}

// ---------------- GEMM1: out[r][c] = (sum_k X[r][k]*W[k][c]) * dinv[r], bf16 out ----
// K=128, M=128. Block: 256 threads, 32 rows. Thread: 4 rows x 4 cols.
__global__ __launch_bounds__(256) void k_gemm1(const float* __restrict__ X,
                                               const float* __restrict__ W,
                                               const float* __restrict__ dinv,
                                               unsigned* __restrict__ out, int N)
{
    constexpr int K = 128, M = 128;
    __shared__ float Ws[K * M];          // 64KB

    const int tid = threadIdx.x;
    for (int idx = tid; idx < K * M / 4; idx += 256)
        reinterpret_cast<float4*>(Ws)[idx] = reinterpret_cast<const float4*>(W)[idx];
    __syncthreads();

    const int cg = tid & 31;
    const int rl = tid >> 5;
    const int rbase = blockIdx.x * 32;

    int rr[4];
#pragma unroll
    for (int i = 0; i < 4; ++i) {
        int r = rbase + rl + 8 * i;
        rr[i] = (r < N) ? r : (N - 1);
    }

    float acc[4][4];
#pragma unroll
    for (int i = 0; i < 4; ++i)
#pragma unroll
        for (int c = 0; c < 4; ++c) acc[i][c] = 0.f;

    const float4* Xg = reinterpret_cast<const float4*>(X);

    for (int kq = 0; kq < K / 4; ++kq) {
        float4 xq[4];
#pragma unroll
        for (int i = 0; i < 4; ++i)
            xq[i] = Xg[(size_t)rr[i] * (K / 4) + kq];
#pragma unroll
        for (int kk = 0; kk < 4; ++kk) {
            float4 w4 = *reinterpret_cast<const float4*>(&Ws[(kq * 4 + kk) * M + cg * 4]);
#pragma unroll
            for (int i = 0; i < 4; ++i) {
                const float* xf = reinterpret_cast<const float*>(&xq[i]);
                float xv = xf[kk];
                acc[i][0] += xv * w4.x; acc[i][1] += xv * w4.y;
                acc[i][2] += xv * w4.z; acc[i][3] += xv * w4.w;
            }
        }
    }

#pragma unroll
    for (int i = 0; i < 4; ++i) {
        int r = rbase + rl + 8 * i;
        if (r >= N) continue;
        float s = dinv[r];
        uint2 o;
        o.x = pack_bf2(acc[i][0] * s, acc[i][1] * s);
        o.y = pack_bf2(acc[i][2] * s, acc[i][3] * s);
        *reinterpret_cast<uint2*>(&out[(size_t)r * (M / 2) + cg * 2]) = o;
    }
}

// ---------------- GEMM2: bf16 in (pre-scaled), f32 math, bf16 out, M=64 ----
__global__ __launch_bounds__(256) void k_gemm2(const unsigned* __restrict__ X,  // bf16x2
                                               const float* __restrict__ W,
                                               unsigned* __restrict__ out, int N)
{
    constexpr int K = 128, M = 64;
    __shared__ float Ws[K * M];          // 32KB

    const int tid = threadIdx.x;
    for (int idx = tid; idx < K * M / 4; idx += 256)
        reinterpret_cast<float4*>(Ws)[idx] = reinterpret_cast<const float4*>(W)[idx];
    __syncthreads();

    const int cg = tid & 31;
    const int rl = tid >> 5;
    const int rbase = blockIdx.x * 32;

    int rr[4];
#pragma unroll
    for (int i = 0; i < 4; ++i) {
        int r = rbase + rl + 8 * i;
        rr[i] = (r < N) ? r : (N - 1);
    }

    float acc[4][2];
#pragma unroll
    for (int i = 0; i < 4; ++i) { acc[i][0] = 0.f; acc[i][1] = 0.f; }

    const uint2* Xg = reinterpret_cast<const uint2*>(X);  // 4 bf16 per uint2

    for (int kq = 0; kq < K / 4; ++kq) {
        uint2 xp[4];
#pragma unroll
        for (int i = 0; i < 4; ++i)
            xp[i] = Xg[(size_t)rr[i] * (K / 4) + kq];
#pragma unroll
        for (int kk = 0; kk < 4; ++kk) {
            float2 w2 = *reinterpret_cast<const float2*>(&Ws[(kq * 4 + kk) * M + cg * 2]);
#pragma unroll
            for (int i = 0; i < 4; ++i) {
                unsigned p = (kk < 2) ? xp[i].x : xp[i].y;
                float xv = (kk & 1) ? bf_hi(p) : bf_lo(p);
                acc[i][0] += xv * w2.x;
                acc[i][1] += xv * w2.y;
            }
        }
    }

#pragma unroll
    for (int i = 0; i < 4; ++i) {
        int r = rbase + rl + 8 * i;
        if (r >= N) continue;
        out[(size_t)r * (M / 2) + cg] = pack_bf2(acc[i][0], acc[i][1]);
    }
}

// ---------------- Layer-1 aggregation + bias + SELU + pre-scale (bf16 H) ----------
// one wave per node; lane holds 2 feats (packed bf16). Index row loaded coalesced
// by the whole wave, broadcast via readlane.
__global__ __launch_bounds__(256) void k_agg1(const unsigned* __restrict__ H,  // bf16x2
                                              const int* __restrict__ csr,
                                              const unsigned* __restrict__ cnt,
                                              const float* __restrict__ dinv,
                                              const float* __restrict__ b1,
                                              unsigned* __restrict__ out, int N)
{
    const int wave = threadIdx.x >> 6;
    const int lane = threadIdx.x & 63;
    const int n = blockIdx.x * 4 + wave;
    if (n >= N) return;

    const int* lst = csr + (size_t)n * CAP;
    int myidx = lst[lane];                       // whole CAP row, one coalesced load
    unsigned c = cnt[n]; if (c > CAP) c = CAP;

    unsigned p0 = H[(size_t)n * 64 + lane];      // self-loop term
    float ax = bf_lo(p0), ay = bf_hi(p0);

    for (unsigned i = 0; i < c; ++i) {
        int s = __builtin_amdgcn_readlane(myidx, i);   // i is wave-uniform
        unsigned p = H[(size_t)s * 64 + lane];
        ax += bf_lo(p); ay += bf_hi(p);
    }
    const float d = dinv[n];
    const float2 b = reinterpret_cast<const float2*>(b1)[lane];
    float tx = ax * d + b.x;
    float ty = ay * d + b.y;
    const float SC = 1.0507009873554805f, AL = 1.6732632423543773f;
    tx = (tx > 0.f) ? SC * tx : SC * AL * (expf(tx) - 1.f);
    ty = (ty > 0.f) ? SC * ty : SC * AL * (expf(ty) - 1.f);
    out[(size_t)n * 64 + lane] = pack_bf2(tx * d, ty * d);   // fold dinv for layer 2
}

// ---------------- Layer-2 aggregation + bias + log_softmax (bf16 H, f32 out) -------
__global__ __launch_bounds__(256) void k_agg2(const unsigned short* __restrict__ H, // bf16
                                              const int* __restrict__ csr,
                                              const unsigned* __restrict__ cnt,
                                              const float* __restrict__ dinv,
                                              const float* __restrict__ b2,
                                              float* __restrict__ out, int N)
{
    const int wave = threadIdx.x >> 6;
    const int lane = threadIdx.x & 63;
    const int n = blockIdx.x * 4 + wave;
    if (n >= N) return;

    const int* lst = csr + (size_t)n * CAP;
    int myidx = lst[lane];
    unsigned c = cnt[n]; if (c > CAP) c = CAP;

    float acc = bf_lo((unsigned)H[(size_t)n * 64 + lane]);   // self-loop term
    for (unsigned i = 0; i < c; ++i) {
        int s = __builtin_amdgcn_readlane(myidx, i);
        acc += bf_lo((unsigned)H[(size_t)s * 64 + lane]);
    }
    float t = acc * dinv[n] + b2[lane];

    float m = t;
#pragma unroll
    for (int off = 32; off > 0; off >>= 1) m = fmaxf(m, __shfl_xor(m, off));
    float e = expf(t - m);
    float ssum = e;
#pragma unroll
    for (int off = 32; off > 0; off >>= 1) ssum += __shfl_xor(ssum, off);
    out[(size_t)n * 64 + lane] = t - m - logf(ssum);
}

// ---------------- host ----------------
extern "C" void kernel_launch(void* const* d_in, const int* in_sizes, int n_in,
                              void* d_out, int out_size, void* d_ws, size_t ws_size,
                              hipStream_t stream)
{
    const float* x  = (const float*)d_in[0];
    const int*   ei = (const int*)  d_in[1];
    const float* W1 = (const float*)d_in[2];
    const float* b1 = (const float*)d_in[3];
    const float* W2 = (const float*)d_in[4];
    const float* b2 = (const float*)d_in[5];
    float* out = (float*)d_out;

    const int N = in_sizes[0] / D_IN;
    const int E = in_sizes[1] / 2;
    const int* src = ei;
    const int* dst = ei + E;

    char* ws = (char*)d_ws;
    size_t off = 0;
    auto take = [&](size_t bytes) -> void* {
        void* p = ws + off;
        off = (off + bytes + 255) & ~(size_t)255;
        return p;
    };
    unsigned* cnt  = (unsigned*)take((size_t)N * 4);
    float*    dinv = (float*)   take((size_t)N * 4);
    int*      csr  = (int*)     take((size_t)N * CAP * 4);
    unsigned* bufA = (unsigned*)take((size_t)N * D_H * 2);   // H1 bf16, pre-scaled
    unsigned* bufB = (unsigned*)take((size_t)N * D_H * 2);   // selu out bf16, pre-scaled
    unsigned* bufC = bufA;                                   // H2 bf16 (reuse)

    hipMemsetAsync(cnt, 0, (size_t)N * 4, stream);
    k_fill<<<(E + 255) / 256, 256, 0, stream>>>(src, dst, cnt, csr, E);
    k_dinv<<<(N + 255) / 256, 256, 0, stream>>>(cnt, dinv, N);
    k_gemm1<<<(N + 31) / 32, 256, 0, stream>>>(x, W1, dinv, bufA, N);
    k_agg1<<<(N + 3) / 4, 256, 0, stream>>>(bufA, csr, cnt, dinv, b1, bufB, N);
    k_gemm2<<<(N + 31) / 32, 256, 0, stream>>>(bufB, W2, bufC, N);
    k_agg2<<<(N + 3) / 4, 256, 0, stream>>>((const unsigned short*)bufC, csr, cnt, dinv, b2, out, N);
}